// Round 8
// baseline (341.071 us; speedup 1.0000x reference)
//
#include <hip/hip_runtime.h>

// Problem constants: B=8, C=4, H=W=512, K_ITERS=10, ALPHA=2
#define Wd   512
#define W4   128               // float4 granules per row (fp32 path)
#define W8   64                // half8 granules per row (fp16 path)
#define HWp  262144            // elements per (b,c) plane
#define NTOT 8388608           // B*C*H*W

#define CHUNK 8                // rows per block (fp16 passes)
#define LROWS 10               // CHUNK + 2 halo rows in LDS
#define LGRAN (LROWS * W8)     // 640 half8 granules per tile

#define F_INF __int_as_float(0x7F800000)

typedef _Float16 half8 __attribute__((ext_vector_type(8)));
typedef _Float16 half4v __attribute__((ext_vector_type(4)));

// red[] layout (960 floats, ALL zero-init; per-iteration slots):
//   cmn[k][plane] = red[k*32 + plane]        unsigned ~bits(min)
//   mx [k][plane] = red[320 + k*32 + plane]  float bits, signed atomicMax
//   sm [k][plane] = red[640 + k*32 + plane]  float atomicAdd

__device__ __forceinline__ float4 bound4(const float* __restrict__ pred,
                                         const int* __restrict__ target,
                                         int plane, int v)
{
    const int b = plane >> 2, c = plane & 3;
    float4 p = ((const float4*)(pred + (size_t)plane * HWp))[v];
    int4   t = ((const int4*)(target + (size_t)b * HWp))[v];
    float dx = p.x - (t.x == c ? 1.0f : 0.0f);
    float dy = p.y - (t.y == c ? 1.0f : 0.0f);
    float dz = p.z - (t.z == c ? 1.0f : 0.0f);
    float dw = p.w - (t.w == c ? 1.0f : 0.0f);
    return make_float4(dx*dx, dy*dy, dz*dz, dw*dw);
}

__device__ __forceinline__ float bound1(const float* __restrict__ pred,
                                        const int* __restrict__ target,
                                        int plane, int i)
{
    const int b = plane >> 2, c = plane & 3;
    float p = pred[(size_t)plane * HWp + i];
    int   t = target[(size_t)b * HWp + i];
    float d = p - (t == c ? 1.0f : 0.0f);
    return d * d;
}

__device__ __forceinline__ void block_reduce_commit(float lmin, float lmax,
                                                    float lsum,
                                                    float* __restrict__ red,
                                                    int k, int plane)
{
    for (int off = 32; off > 0; off >>= 1) {
        lmin = fminf(lmin, __shfl_down(lmin, off));
        lmax = fmaxf(lmax, __shfl_down(lmax, off));
        lsum += __shfl_down(lsum, off);
    }
    __shared__ float smin[4], smax[4], ssum[4];
    const int wave = threadIdx.x >> 6;
    if ((threadIdx.x & 63) == 0) { smin[wave] = lmin; smax[wave] = lmax; ssum[wave] = lsum; }
    __syncthreads();
    if (threadIdx.x == 0) {
        float bmin = smin[0], bmax = smax[0], bsum = ssum[0];
        for (int i = 1; i < 4; i++) {
            bmin = fminf(bmin, smin[i]);
            bmax = fmaxf(bmax, smax[i]);
            bsum += ssum[i];
        }
        atomicMax((unsigned*)&red[k * 32 + plane], ~__float_as_uint(bmin));
        atomicMax((int*)&red[320 + k * 32 + plane], __float_as_int(bmax));
        atomicAdd(&red[640 + k * 32 + plane], bsum);
    }
}

// k=0: bound from pred/target (fp32 inputs), OUTPUT stored as fp16.
// Round-4-verified structure, unchanged. Stats on fp16-ROUNDED values so
// pass 1 (which reads fp16) normalizes consistently.
__global__ __launch_bounds__(256) void stencil_first(const float* __restrict__ pred,
                                                     const int* __restrict__ target,
                                                     _Float16* __restrict__ out,
                                                     float* __restrict__ red)
{
    const int plane = blockIdx.y;
    const int chunk = blockIdx.x;              // 16 rows per chunk

    _Float16* op = out + (size_t)plane * HWp;

    const int col4 = threadIdx.x & 127;
    const int rsub = threadIdx.x >> 7;

    float lmin = F_INF, lmax = 0.0f, lsum = 0.0f;
    const bool hasL = (col4 > 0);
    const bool hasR = (col4 < W4 - 1);

    #pragma unroll
    for (int p = 0; p < 8; p++) {
        const int row = chunk * 16 + p * 2 + rsub;
        const int v   = row * W4 + col4;
        const bool hasU = (row > 0);
        const bool hasD = (row < Wd - 1);

        float4 c4 = bound4(pred, target, plane, v);
        float4 u4 = hasU ? bound4(pred, target, plane, v - W4) : make_float4(0,0,0,0);
        float4 d4 = hasD ? bound4(pred, target, plane, v + W4) : make_float4(0,0,0,0);
        float lft = hasL ? bound1(pred, target, plane, 4*v - 1) : 0.0f;
        float rgt = hasR ? bound1(pred, target, plane, 4*v + 4) : 0.0f;

        float4 sum;
        sum.x = c4.x + c4.y + u4.x + d4.x + lft;
        sum.y = c4.x + c4.y + c4.z + u4.y + d4.y;
        sum.z = c4.y + c4.z + c4.w + u4.z + d4.z;
        sum.w = c4.z + c4.w + rgt + u4.w + d4.w;

        float4 e;
        e.x = fmaxf(0.2f * sum.x - 0.5f, 0.0f);   // k=0: s=1, o=0
        e.y = fmaxf(0.2f * sum.y - 0.5f, 0.0f);
        e.z = fmaxf(0.2f * sum.z - 0.5f, 0.0f);
        e.w = fmaxf(0.2f * sum.w - 0.5f, 0.0f);

        half4v h;
        h[0] = (_Float16)e.x; h[1] = (_Float16)e.y;
        h[2] = (_Float16)e.z; h[3] = (_Float16)e.w;
        ((half4v*)op)[v] = h;

        float r0 = (float)h[0], r1 = (float)h[1], r2 = (float)h[2], r3 = (float)h[3];
        lmin = fminf(lmin, fminf(fminf(r0, r1), fminf(r2, r3)));
        lmax = fmaxf(lmax, fmaxf(fmaxf(r0, r1), fmaxf(r2, r3)));
        lsum += (r0 + r1) + (r2 + r3);
    }

    block_reduce_commit(lmin, lmax, lsum, red, 0, plane);
}

// k>=1: fp16 in -> fp16 out via LDS tile.
// Grid 64 chunks (8 rows) x 32 planes = 2048 blocks, 8 blocks/CU
// (launch_bounds(256,8)) = 32 waves/CU. Stage 10 rows (8 + 2 halo) into
// LDS with 3 back-to-back masked half8 loads/thread (each element read
// from global ONCE; ~96 outstanding requests/CU hides L2/L3 latency with
// only ~16 transient VGPRs -> fits the <=64-VGPR occupancy bin that the
// register-resident body could not). Left/right neighbors come from
// __shfl of the converted center row (each wave owns a full 512-wide
// row), so no scalar LDS reads. All LDS traffic is wave-uniform-row
// contiguous 1KB -> conflict-free. Arithmetic identical to round 6.
__global__ __launch_bounds__(256, 8) void stencil_h(const _Float16* __restrict__ in,
                                                    _Float16* __restrict__ out,
                                                    float* __restrict__ red,
                                                    int k, int store)
{
    const int plane = blockIdx.y;
    const int chunk = blockIdx.x;              // 8 rows per chunk
    const int r0    = chunk * CHUNK;

    float mn = __uint_as_float(~((const unsigned*)red)[(k - 1) * 32 + plane]);
    float mx = red[320 + (k - 1) * 32 + plane];
    float denom = mx - mn;
    float s = 1.0f, o = 0.0f;
    if (denom != 0.0f) { s = 1.0f / denom; o = -mn / denom; }

    const _Float16* ip = in  + (size_t)plane * HWp;
    _Float16*       op = out + (size_t)plane * HWp;

    __shared__ _Float16 tile[LROWS][512];

    const int tid = threadIdx.x;

    // ---- stage: 640 granules / 256 threads = 3 masked rounds ----
    half8 st[3];
    #pragma unroll
    for (int i = 0; i < 3; i++) {
        const int g    = tid + i * 256;
        const int lrow = g >> 6, lcol = g & 63;
        const int grow = r0 - 1 + lrow;        // global row of LDS row
        half8 v = (half8)(_Float16)0;
        if (g < LGRAN && grow >= 0 && grow < Wd)
            v = ((const half8*)ip)[grow * W8 + lcol];
        st[i] = v;
    }
    #pragma unroll
    for (int i = 0; i < 3; i++) {
        const int g = tid + i * 256;
        if (g < LGRAN)
            ((half8*)&tile[g >> 6][0])[g & 63] = st[i];
    }
    __syncthreads();

    // ---- compute: each wave owns full rows (lane == col8) ----
    const int col8 = tid & 63;                 // == lane
    const int rsub = tid >> 6;                 // 0..3
    const bool hasL = (col8 > 0);
    const bool hasR = (col8 < W8 - 1);

    float lmin = F_INF, lmax = 0.0f, lsum = 0.0f;

    #pragma unroll
    for (int p = 0; p < 2; p++) {
        const int  row  = r0 + p * 4 + rsub;   // global row
        const int  lrow = 1 + p * 4 + rsub;    // LDS row of center
        const bool hasU = (row > 0);
        const bool hasD = (row < Wd - 1);

        half8 c8 = ((const half8*)&tile[lrow][0])[col8];
        half8 u8 = ((const half8*)&tile[lrow - 1][0])[col8];
        half8 d8 = ((const half8*)&tile[lrow + 1][0])[col8];

        float cf[8], uf[8], df[8];
        #pragma unroll
        for (int j = 0; j < 8; j++) {
            cf[j] = (float)c8[j]; uf[j] = (float)u8[j]; df[j] = (float)d8[j];
        }

        // row-neighbors across granules via wave shuffle (wave == row)
        float lft = __shfl_up(cf[7], 1);       // lane 0 masked by hasL
        float rgt = __shfl_down(cf[0], 1);     // lane 63 masked by hasR
        if (!hasL) lft = 0.0f;
        if (!hasR) rgt = 0.0f;

        const float vc = (hasU ? 1.0f : 0.0f) + (hasD ? 1.0f : 0.0f);
        half8 eh;
        #pragma unroll
        for (int j = 0; j < 8; j++) {
            const float lnb = (j == 0) ? lft : cf[j - 1];
            const float rnb = (j == 7) ? rgt : cf[j + 1];
            const bool  hl  = (j > 0) || hasL;
            const bool  hr  = (j < 7) || hasR;
            float sum = cf[j] + lnb + rnb + uf[j] + df[j];
            float cnt = 1.0f + (hl ? 1.0f : 0.0f) + (hr ? 1.0f : 0.0f) + vc;
            float e = fmaxf(0.2f * (s * sum + o * cnt) - 0.5f, 0.0f);
            _Float16 h = (_Float16)e;
            eh[j] = h;
            float er = (float)h;               // rounded value for stats
            lmin = fminf(lmin, er);
            lmax = fmaxf(lmax, er);
            lsum += er;
        }

        if (store) ((half8*)op)[row * W8 + col8] = eh;
    }

    block_reduce_commit(lmin, lmax, lsum, red, k, plane);
}

// One block, 64 threads: fold all 10x32 plane reductions into the scalar.
__global__ void final_out(const float* __restrict__ red, float* __restrict__ out)
{
    const int lane = threadIdx.x;
    float contrib = 0.0f;
    if (lane < 32) {
        #pragma unroll
        for (int kk = 0; kk < 10; kk++) {
            float mn = __uint_as_float(~((const unsigned*)red)[kk * 32 + lane]);
            float mx = red[320 + kk * 32 + lane];
            float sm = red[640 + kk * 32 + lane];
            float denom = mx - mn;
            float ss = 1.0f, oo = 0.0f;
            if (denom != 0.0f) { ss = 1.0f / denom; oo = -mn / denom; }
            float w = (float)((kk + 1) * (kk + 1));
            contrib += (ss * sm + oo * 262144.0f) * w;
        }
    }
    for (int off = 16; off > 0; off >>= 1)
        contrib += __shfl_down(contrib, off);
    if (lane == 0) out[0] = contrib / 8388608.0f;
}

extern "C" void kernel_launch(void* const* d_in, const int* in_sizes, int n_in,
                              void* d_out, int out_size, void* d_ws, size_t ws_size,
                              hipStream_t stream)
{
    const float* pred   = (const float*)d_in[0];
    const int*   target = (const int*)d_in[1];
    float* out = (float*)d_out;

    _Float16* h0  = (_Float16*)d_ws;
    _Float16* h1  = h0 + NTOT;
    float*    red = (float*)(h1 + NTOT);

    // all reduction slots zero-init (min stored as complement)
    hipMemsetAsync((void*)red, 0, 960 * sizeof(float), stream);

    dim3 gridF(32, 32);   // first pass: 16-row chunks (round-4 verified)
    stencil_first<<<gridF, 256, 0, stream>>>(pred, target, h0, red);

    dim3 gridH(64, 32);   // fp16 passes: 8-row chunks, 2048 blocks
    const _Float16* a = h0;
    _Float16*       b = h1;
    for (int k = 1; k < 10; k++) {
        stencil_h<<<gridH, 256, 0, stream>>>(a, b, red, k, (k < 9) ? 1 : 0);
        const _Float16* t = a; a = b; b = (_Float16*)t;
    }
    final_out<<<1, 64, 0, stream>>>(red, out);
}

// Round 9
// 245.411 us; speedup vs baseline: 1.3898x; 1.3898x over previous
//
#include <hip/hip_runtime.h>

// Problem constants: B=8, C=4, H=W=512, K_ITERS=10, ALPHA=2
#define Wd   512
#define W4   128               // float4 granules per row (fp32 path)
#define W8   64                // half8 granules per row (fp16 path)
#define HWp  262144            // elements per (b,c) plane
#define NTOT 8388608           // B*C*H*W

#define F_INF __int_as_float(0x7F800000)

typedef _Float16 half8 __attribute__((ext_vector_type(8)));
typedef _Float16 half4v __attribute__((ext_vector_type(4)));

// red[] layout (960 floats, ALL zero-init; per-iteration slots):
//   cmn[k][plane] = red[k*32 + plane]        unsigned ~bits(min)
//   mx [k][plane] = red[320 + k*32 + plane]  float bits, signed atomicMax
//   sm [k][plane] = red[640 + k*32 + plane]  float atomicAdd

__device__ __forceinline__ float4 bound4(const float* __restrict__ pred,
                                         const int* __restrict__ target,
                                         int plane, int v)
{
    const int b = plane >> 2, c = plane & 3;
    float4 p = ((const float4*)(pred + (size_t)plane * HWp))[v];
    int4   t = ((const int4*)(target + (size_t)b * HWp))[v];
    float dx = p.x - (t.x == c ? 1.0f : 0.0f);
    float dy = p.y - (t.y == c ? 1.0f : 0.0f);
    float dz = p.z - (t.z == c ? 1.0f : 0.0f);
    float dw = p.w - (t.w == c ? 1.0f : 0.0f);
    return make_float4(dx*dx, dy*dy, dz*dz, dw*dw);
}

__device__ __forceinline__ float bound1(const float* __restrict__ pred,
                                        const int* __restrict__ target,
                                        int plane, int i)
{
    const int b = plane >> 2, c = plane & 3;
    float p = pred[(size_t)plane * HWp + i];
    int   t = target[(size_t)b * HWp + i];
    float d = p - (t == c ? 1.0f : 0.0f);
    return d * d;
}

__device__ __forceinline__ void block_reduce_commit(float lmin, float lmax,
                                                    float lsum,
                                                    float* __restrict__ red,
                                                    int k, int plane)
{
    for (int off = 32; off > 0; off >>= 1) {
        lmin = fminf(lmin, __shfl_down(lmin, off));
        lmax = fmaxf(lmax, __shfl_down(lmax, off));
        lsum += __shfl_down(lsum, off);
    }
    __shared__ float smin[4], smax[4], ssum[4];
    const int wave = threadIdx.x >> 6;
    if ((threadIdx.x & 63) == 0) { smin[wave] = lmin; smax[wave] = lmax; ssum[wave] = lsum; }
    __syncthreads();
    if (threadIdx.x == 0) {
        float bmin = smin[0], bmax = smax[0], bsum = ssum[0];
        for (int i = 1; i < 4; i++) {
            bmin = fminf(bmin, smin[i]);
            bmax = fmaxf(bmax, smax[i]);
            bsum += ssum[i];
        }
        atomicMax((unsigned*)&red[k * 32 + plane], ~__float_as_uint(bmin));
        atomicMax((int*)&red[320 + k * 32 + plane], __float_as_int(bmax));
        atomicAdd(&red[640 + k * 32 + plane], bsum);
    }
}

// k=0: bound from pred/target (fp32 inputs), OUTPUT stored as fp16.
// Round-4-verified structure, unchanged. Stats on fp16-ROUNDED values so
// pass 1 (which reads fp16) normalizes consistently.
__global__ __launch_bounds__(256) void stencil_first(const float* __restrict__ pred,
                                                     const int* __restrict__ target,
                                                     _Float16* __restrict__ out,
                                                     float* __restrict__ red)
{
    const int plane = blockIdx.y;
    const int chunk = blockIdx.x;              // 16 rows per chunk

    _Float16* op = out + (size_t)plane * HWp;

    const int col4 = threadIdx.x & 127;
    const int rsub = threadIdx.x >> 7;

    float lmin = F_INF, lmax = 0.0f, lsum = 0.0f;
    const bool hasL = (col4 > 0);
    const bool hasR = (col4 < W4 - 1);

    #pragma unroll
    for (int p = 0; p < 8; p++) {
        const int row = chunk * 16 + p * 2 + rsub;
        const int v   = row * W4 + col4;
        const bool hasU = (row > 0);
        const bool hasD = (row < Wd - 1);

        float4 c4 = bound4(pred, target, plane, v);
        float4 u4 = hasU ? bound4(pred, target, plane, v - W4) : make_float4(0,0,0,0);
        float4 d4 = hasD ? bound4(pred, target, plane, v + W4) : make_float4(0,0,0,0);
        float lft = hasL ? bound1(pred, target, plane, 4*v - 1) : 0.0f;
        float rgt = hasR ? bound1(pred, target, plane, 4*v + 4) : 0.0f;

        float4 sum;
        sum.x = c4.x + c4.y + u4.x + d4.x + lft;
        sum.y = c4.x + c4.y + c4.z + u4.y + d4.y;
        sum.z = c4.y + c4.z + c4.w + u4.z + d4.z;
        sum.w = c4.z + c4.w + rgt + u4.w + d4.w;

        float4 e;
        e.x = fmaxf(0.2f * sum.x - 0.5f, 0.0f);   // k=0: s=1, o=0
        e.y = fmaxf(0.2f * sum.y - 0.5f, 0.0f);
        e.z = fmaxf(0.2f * sum.z - 0.5f, 0.0f);
        e.w = fmaxf(0.2f * sum.w - 0.5f, 0.0f);

        half4v h;
        h[0] = (_Float16)e.x; h[1] = (_Float16)e.y;
        h[2] = (_Float16)e.z; h[3] = (_Float16)e.w;
        ((half4v*)op)[v] = h;

        float r0 = (float)h[0], r1 = (float)h[1], r2 = (float)h[2], r3 = (float)h[3];
        lmin = fminf(lmin, fminf(fminf(r0, r1), fminf(r2, r3)));
        lmax = fmaxf(lmax, fmaxf(fmaxf(r0, r1), fmaxf(r2, r3)));
        lsum += (r0 + r1) + (r2 + r3);
    }

    block_reduce_commit(lmin, lmax, lsum, red, 0, plane);
}

// k>=1: fp16 in -> fp16 out, register-resident, burst-issue body.
// Grid (32 chunks x 32 planes) = 1024 blocks, NO min-waves bound
// (rounds 3/5/8: every VGPR-capped variant spilled/serialized -> big
// regressions). Each thread owns 4 CONSECUTIVE rows and issues all 6
// half8 loads (4 center + 2 halo) in one burst before any conversion ->
// ~2x outstanding requests per wave vs the step-wise round-6 body, one
// vmcnt wait instead of four. Each wave owns full 512-wide rows (lane ==
// col8), so left/right neighbors come from wave shuffles (round-8
// verified, absmax 0.0) -- no 2-byte scalar edge loads at all.
__global__ __launch_bounds__(256) void stencil_h(const _Float16* __restrict__ in,
                                                 _Float16* __restrict__ out,
                                                 float* __restrict__ red,
                                                 int k, int store)
{
    const int plane = blockIdx.y;
    const int chunk = blockIdx.x;              // 16 rows per chunk

    float mn = __uint_as_float(~((const unsigned*)red)[(k - 1) * 32 + plane]);
    float mx = red[320 + (k - 1) * 32 + plane];
    float denom = mx - mn;
    float s = 1.0f, o = 0.0f;
    if (denom != 0.0f) { s = 1.0f / denom; o = -mn / denom; }

    const _Float16* ip = in  + (size_t)plane * HWp;
    _Float16*       op = out + (size_t)plane * HWp;

    const int col8 = threadIdx.x & 63;         // == lane; half8 column
    const int rsub = threadIdx.x >> 6;         // 0..3 (== wave index)
    const int r0   = chunk * 16 + rsub * 4;    // 4 consecutive rows
    const int v0   = r0 * W8 + col8;

    const bool hasL  = (col8 > 0);
    const bool hasR  = (col8 < W8 - 1);
    const bool hasU0 = (r0 > 0);
    const bool hasD3 = (r0 + 4 < Wd);

    // ---- burst: all 6 vector loads issued back-to-back ----
    half8 u8 = hasU0 ? ((const half8*)ip)[v0 - W8]     : (half8)(_Float16)0;
    half8 c0 = ((const half8*)ip)[v0];
    half8 c1 = ((const half8*)ip)[v0 + W8];
    half8 c2 = ((const half8*)ip)[v0 + 2 * W8];
    half8 c3 = ((const half8*)ip)[v0 + 3 * W8];
    half8 d8 = hasD3 ? ((const half8*)ip)[v0 + 4 * W8] : (half8)(_Float16)0;

    // ---- convert once to float (static indexing only) ----
    float uf[8], f0[8], f1[8], f2[8], f3[8], df[8];
    #pragma unroll
    for (int j = 0; j < 8; j++) {
        uf[j] = (float)u8[j];
        f0[j] = (float)c0[j]; f1[j] = (float)c1[j];
        f2[j] = (float)c2[j]; f3[j] = (float)c3[j];
        df[j] = (float)d8[j];
    }

    float lmin = F_INF, lmax = 0.0f, lsum = 0.0f;

    auto PROC = [&](const float* up, const float* cen, const float* dn, int row) {
        const bool hasU = (row > 0);
        const bool hasD = (row < Wd - 1);
        // row neighbors across granules via wave shuffle (wave == row band)
        float lft = __shfl_up(cen[7], 1);      // lane 0 masked by hasL
        float rgt = __shfl_down(cen[0], 1);    // lane 63 masked by hasR
        if (!hasL) lft = 0.0f;
        if (!hasR) rgt = 0.0f;

        const float vc = (hasU ? 1.0f : 0.0f) + (hasD ? 1.0f : 0.0f);
        half8 eh;
        #pragma unroll
        for (int j = 0; j < 8; j++) {
            const float lnb = (j == 0) ? lft : cen[j - 1];
            const float rnb = (j == 7) ? rgt : cen[j + 1];
            const bool  hl  = (j > 0) || hasL;
            const bool  hr  = (j < 7) || hasR;
            float sum = cen[j] + lnb + rnb + up[j] + dn[j];
            float cnt = 1.0f + (hl ? 1.0f : 0.0f) + (hr ? 1.0f : 0.0f) + vc;
            float e = fmaxf(0.2f * (s * sum + o * cnt) - 0.5f, 0.0f);
            _Float16 h = (_Float16)e;
            eh[j] = h;
            float er = (float)h;               // rounded value for stats
            lmin = fminf(lmin, er);
            lmax = fmaxf(lmax, er);
            lsum += er;
        }
        if (store) ((half8*)op)[row * W8 + col8] = eh;
    };

    PROC(uf, f0, f1, r0);
    PROC(f0, f1, f2, r0 + 1);
    PROC(f1, f2, f3, r0 + 2);
    PROC(f2, f3, df, r0 + 3);

    block_reduce_commit(lmin, lmax, lsum, red, k, plane);
}

// One block, 64 threads: fold all 10x32 plane reductions into the scalar.
__global__ void final_out(const float* __restrict__ red, float* __restrict__ out)
{
    const int lane = threadIdx.x;
    float contrib = 0.0f;
    if (lane < 32) {
        #pragma unroll
        for (int kk = 0; kk < 10; kk++) {
            float mn = __uint_as_float(~((const unsigned*)red)[kk * 32 + lane]);
            float mx = red[320 + kk * 32 + lane];
            float sm = red[640 + kk * 32 + lane];
            float denom = mx - mn;
            float ss = 1.0f, oo = 0.0f;
            if (denom != 0.0f) { ss = 1.0f / denom; oo = -mn / denom; }
            float w = (float)((kk + 1) * (kk + 1));
            contrib += (ss * sm + oo * 262144.0f) * w;
        }
    }
    for (int off = 16; off > 0; off >>= 1)
        contrib += __shfl_down(contrib, off);
    if (lane == 0) out[0] = contrib / 8388608.0f;
}

extern "C" void kernel_launch(void* const* d_in, const int* in_sizes, int n_in,
                              void* d_out, int out_size, void* d_ws, size_t ws_size,
                              hipStream_t stream)
{
    const float* pred   = (const float*)d_in[0];
    const int*   target = (const int*)d_in[1];
    float* out = (float*)d_out;

    _Float16* h0  = (_Float16*)d_ws;
    _Float16* h1  = h0 + NTOT;
    float*    red = (float*)(h1 + NTOT);

    // all reduction slots zero-init (min stored as complement)
    hipMemsetAsync((void*)red, 0, 960 * sizeof(float), stream);

    dim3 grid(32, 32);   // 32 chunks of 16 rows x 32 planes = 1024 blocks
    stencil_first<<<grid, 256, 0, stream>>>(pred, target, h0, red);

    const _Float16* a = h0;
    _Float16*       b = h1;
    for (int k = 1; k < 10; k++) {
        stencil_h<<<grid, 256, 0, stream>>>(a, b, red, k, (k < 9) ? 1 : 0);
        const _Float16* t = a; a = b; b = (_Float16*)t;
    }
    final_out<<<1, 64, 0, stream>>>(red, out);
}

// Round 10
// 240.766 us; speedup vs baseline: 1.4166x; 1.0193x over previous
//
#include <hip/hip_runtime.h>

// Problem constants: B=8, C=4, H=W=512, K_ITERS=10, ALPHA=2
#define Wd   512
#define W4   128               // float4 granules per row (fp32 path)
#define W8   64                // half8 granules per row (fp16 path)
#define HWp  262144            // elements per (b,c) plane
#define NTOT 8388608           // B*C*H*W

#define F_INF __int_as_float(0x7F800000)

typedef _Float16 half8 __attribute__((ext_vector_type(8)));
typedef _Float16 half4v __attribute__((ext_vector_type(4)));

// red[] layout (960 floats, ALL zero-init; per-iteration slots):
//   cmn[k][plane] = red[k*32 + plane]        unsigned ~bits(min)
//   mx [k][plane] = red[320 + k*32 + plane]  float bits, signed atomicMax
//   sm [k][plane] = red[640 + k*32 + plane]  float atomicAdd

__device__ __forceinline__ float4 bound4(const float* __restrict__ pred,
                                         const int* __restrict__ target,
                                         int plane, int v)
{
    const int b = plane >> 2, c = plane & 3;
    float4 p = ((const float4*)(pred + (size_t)plane * HWp))[v];
    int4   t = ((const int4*)(target + (size_t)b * HWp))[v];
    float dx = p.x - (t.x == c ? 1.0f : 0.0f);
    float dy = p.y - (t.y == c ? 1.0f : 0.0f);
    float dz = p.z - (t.z == c ? 1.0f : 0.0f);
    float dw = p.w - (t.w == c ? 1.0f : 0.0f);
    return make_float4(dx*dx, dy*dy, dz*dz, dw*dw);
}

__device__ __forceinline__ float bound1(const float* __restrict__ pred,
                                        const int* __restrict__ target,
                                        int plane, int i)
{
    const int b = plane >> 2, c = plane & 3;
    float p = pred[(size_t)plane * HWp + i];
    int   t = target[(size_t)b * HWp + i];
    float d = p - (t == c ? 1.0f : 0.0f);
    return d * d;
}

// NW = number of waves in the block
template <int NW>
__device__ __forceinline__ void block_reduce_commit(float lmin, float lmax,
                                                    float lsum,
                                                    float* __restrict__ red,
                                                    int k, int plane)
{
    for (int off = 32; off > 0; off >>= 1) {
        lmin = fminf(lmin, __shfl_down(lmin, off));
        lmax = fmaxf(lmax, __shfl_down(lmax, off));
        lsum += __shfl_down(lsum, off);
    }
    __shared__ float smin[NW], smax[NW], ssum[NW];
    const int wave = threadIdx.x >> 6;
    if ((threadIdx.x & 63) == 0) { smin[wave] = lmin; smax[wave] = lmax; ssum[wave] = lsum; }
    __syncthreads();
    if (threadIdx.x == 0) {
        float bmin = smin[0], bmax = smax[0], bsum = ssum[0];
        #pragma unroll
        for (int i = 1; i < NW; i++) {
            bmin = fminf(bmin, smin[i]);
            bmax = fmaxf(bmax, smax[i]);
            bsum += ssum[i];
        }
        atomicMax((unsigned*)&red[k * 32 + plane], ~__float_as_uint(bmin));
        atomicMax((int*)&red[320 + k * 32 + plane], __float_as_int(bmax));
        atomicAdd(&red[640 + k * 32 + plane], bsum);
    }
}

// k=0: bound from pred/target (fp32 inputs), OUTPUT stored as fp16.
// Round-4-verified structure, unchanged. Stats on fp16-ROUNDED values so
// pass 1 (which reads fp16) normalizes consistently.
__global__ __launch_bounds__(256) void stencil_first(const float* __restrict__ pred,
                                                     const int* __restrict__ target,
                                                     _Float16* __restrict__ out,
                                                     float* __restrict__ red)
{
    const int plane = blockIdx.y;
    const int chunk = blockIdx.x;              // 16 rows per chunk

    _Float16* op = out + (size_t)plane * HWp;

    const int col4 = threadIdx.x & 127;
    const int rsub = threadIdx.x >> 7;

    float lmin = F_INF, lmax = 0.0f, lsum = 0.0f;
    const bool hasL = (col4 > 0);
    const bool hasR = (col4 < W4 - 1);

    #pragma unroll
    for (int p = 0; p < 8; p++) {
        const int row = chunk * 16 + p * 2 + rsub;
        const int v   = row * W4 + col4;
        const bool hasU = (row > 0);
        const bool hasD = (row < Wd - 1);

        float4 c4 = bound4(pred, target, plane, v);
        float4 u4 = hasU ? bound4(pred, target, plane, v - W4) : make_float4(0,0,0,0);
        float4 d4 = hasD ? bound4(pred, target, plane, v + W4) : make_float4(0,0,0,0);
        float lft = hasL ? bound1(pred, target, plane, 4*v - 1) : 0.0f;
        float rgt = hasR ? bound1(pred, target, plane, 4*v + 4) : 0.0f;

        float4 sum;
        sum.x = c4.x + c4.y + u4.x + d4.x + lft;
        sum.y = c4.x + c4.y + c4.z + u4.y + d4.y;
        sum.z = c4.y + c4.z + c4.w + u4.z + d4.z;
        sum.w = c4.z + c4.w + rgt + u4.w + d4.w;

        float4 e;
        e.x = fmaxf(0.2f * sum.x - 0.5f, 0.0f);   // k=0: s=1, o=0
        e.y = fmaxf(0.2f * sum.y - 0.5f, 0.0f);
        e.z = fmaxf(0.2f * sum.z - 0.5f, 0.0f);
        e.w = fmaxf(0.2f * sum.w - 0.5f, 0.0f);

        half4v h;
        h[0] = (_Float16)e.x; h[1] = (_Float16)e.y;
        h[2] = (_Float16)e.z; h[3] = (_Float16)e.w;
        ((half4v*)op)[v] = h;

        float r0 = (float)h[0], r1 = (float)h[1], r2 = (float)h[2], r3 = (float)h[3];
        lmin = fminf(lmin, fminf(fminf(r0, r1), fminf(r2, r3)));
        lmax = fmaxf(lmax, fmaxf(fmaxf(r0, r1), fmaxf(r2, r3)));
        lsum += (r0 + r1) + (r2 + r3);
    }

    block_reduce_commit<4>(lmin, lmax, lsum, red, 0, plane);
}

// k>=1: fp16 in -> fp16 out, register-resident burst body (round-9
// verified, absmax 0.0), now at 512 threads/block = 8 waves so the SAME
// 1024-block grid carries 8192 waves = 32 waves/CU (round 9: VGPR=36 but
// only 16 waves/CU -> occupancy was GRID-limited). Each wave owns 2
// consecutive full rows; each thread bursts 4 half8 loads (2 center + 2
// halo) -> 128 outstanding requests/CU (vs 96) plus 2x waves to overlap
// the wait chains. NO min-waves bound (rounds 3/5/8: every VGPR cap
// regressed); 2-row body needs ~40-56 VGPR, inside the <=64 bin
// naturally. Left/right neighbors via wave shuffles (wave owns the row).
__global__ __launch_bounds__(512) void stencil_h(const _Float16* __restrict__ in,
                                                 _Float16* __restrict__ out,
                                                 float* __restrict__ red,
                                                 int k, int store)
{
    const int plane = blockIdx.y;
    const int chunk = blockIdx.x;              // 16 rows per chunk

    float mn = __uint_as_float(~((const unsigned*)red)[(k - 1) * 32 + plane]);
    float mx = red[320 + (k - 1) * 32 + plane];
    float denom = mx - mn;
    float s = 1.0f, o = 0.0f;
    if (denom != 0.0f) { s = 1.0f / denom; o = -mn / denom; }

    const _Float16* ip = in  + (size_t)plane * HWp;
    _Float16*       op = out + (size_t)plane * HWp;

    const int col8 = threadIdx.x & 63;         // == lane; half8 column
    const int wv   = threadIdx.x >> 6;         // 0..7 (wave index)
    const int r0   = chunk * 16 + wv * 2;      // 2 consecutive rows
    const int v0   = r0 * W8 + col8;

    const bool hasL  = (col8 > 0);
    const bool hasR  = (col8 < W8 - 1);
    const bool hasU0 = (r0 > 0);
    const bool hasD1 = (r0 + 2 < Wd);

    // ---- burst: all 4 vector loads issued back-to-back ----
    half8 u8 = hasU0 ? ((const half8*)ip)[v0 - W8]     : (half8)(_Float16)0;
    half8 c0 = ((const half8*)ip)[v0];
    half8 c1 = ((const half8*)ip)[v0 + W8];
    half8 d8 = hasD1 ? ((const half8*)ip)[v0 + 2 * W8] : (half8)(_Float16)0;

    // ---- convert once to float (static indexing only) ----
    float uf[8], f0[8], f1[8], df[8];
    #pragma unroll
    for (int j = 0; j < 8; j++) {
        uf[j] = (float)u8[j];
        f0[j] = (float)c0[j]; f1[j] = (float)c1[j];
        df[j] = (float)d8[j];
    }

    float lmin = F_INF, lmax = 0.0f, lsum = 0.0f;

    auto PROC = [&](const float* up, const float* cen, const float* dn, int row) {
        const bool hasU = (row > 0);
        const bool hasD = (row < Wd - 1);
        // row neighbors across granules via wave shuffle (wave owns row)
        float lft = __shfl_up(cen[7], 1);      // lane 0 masked by hasL
        float rgt = __shfl_down(cen[0], 1);    // lane 63 masked by hasR
        if (!hasL) lft = 0.0f;
        if (!hasR) rgt = 0.0f;

        const float vc = (hasU ? 1.0f : 0.0f) + (hasD ? 1.0f : 0.0f);
        half8 eh;
        #pragma unroll
        for (int j = 0; j < 8; j++) {
            const float lnb = (j == 0) ? lft : cen[j - 1];
            const float rnb = (j == 7) ? rgt : cen[j + 1];
            const bool  hl  = (j > 0) || hasL;
            const bool  hr  = (j < 7) || hasR;
            float sum = cen[j] + lnb + rnb + up[j] + dn[j];
            float cnt = 1.0f + (hl ? 1.0f : 0.0f) + (hr ? 1.0f : 0.0f) + vc;
            float e = fmaxf(0.2f * (s * sum + o * cnt) - 0.5f, 0.0f);
            _Float16 h = (_Float16)e;
            eh[j] = h;
            float er = (float)h;               // rounded value for stats
            lmin = fminf(lmin, er);
            lmax = fmaxf(lmax, er);
            lsum += er;
        }
        if (store) ((half8*)op)[row * W8 + col8] = eh;
    };

    PROC(uf, f0, f1, r0);
    PROC(f0, f1, df, r0 + 1);

    block_reduce_commit<8>(lmin, lmax, lsum, red, k, plane);
}

// One block, 64 threads: fold all 10x32 plane reductions into the scalar.
__global__ void final_out(const float* __restrict__ red, float* __restrict__ out)
{
    const int lane = threadIdx.x;
    float contrib = 0.0f;
    if (lane < 32) {
        #pragma unroll
        for (int kk = 0; kk < 10; kk++) {
            float mn = __uint_as_float(~((const unsigned*)red)[kk * 32 + lane]);
            float mx = red[320 + kk * 32 + lane];
            float sm = red[640 + kk * 32 + lane];
            float denom = mx - mn;
            float ss = 1.0f, oo = 0.0f;
            if (denom != 0.0f) { ss = 1.0f / denom; oo = -mn / denom; }
            float w = (float)((kk + 1) * (kk + 1));
            contrib += (ss * sm + oo * 262144.0f) * w;
        }
    }
    for (int off = 16; off > 0; off >>= 1)
        contrib += __shfl_down(contrib, off);
    if (lane == 0) out[0] = contrib / 8388608.0f;
}

extern "C" void kernel_launch(void* const* d_in, const int* in_sizes, int n_in,
                              void* d_out, int out_size, void* d_ws, size_t ws_size,
                              hipStream_t stream)
{
    const float* pred   = (const float*)d_in[0];
    const int*   target = (const int*)d_in[1];
    float* out = (float*)d_out;

    _Float16* h0  = (_Float16*)d_ws;
    _Float16* h1  = h0 + NTOT;
    float*    red = (float*)(h1 + NTOT);

    // all reduction slots zero-init (min stored as complement)
    hipMemsetAsync((void*)red, 0, 960 * sizeof(float), stream);

    dim3 grid(32, 32);   // 32 chunks of 16 rows x 32 planes = 1024 blocks
    stencil_first<<<grid, 256, 0, stream>>>(pred, target, h0, red);

    const _Float16* a = h0;
    _Float16*       b = h1;
    for (int k = 1; k < 10; k++) {
        stencil_h<<<grid, 512, 0, stream>>>(a, b, red, k, (k < 9) ? 1 : 0);
        const _Float16* t = a; a = b; b = (_Float16*)t;
    }
    final_out<<<1, 64, 0, stream>>>(red, out);
}